// Round 8
// baseline (101.600 us; speedup 1.0000x reference)
//
#include <hip/hip_runtime.h>
#include <math.h>

#define NDIM 1024
#define BDIM 128
#define TS 32
#define NT (NDIM / TS)                 // 32
#define NTILES (NT * (NT + 1) / 2)     // 528 upper-tri tiles
#define NHALF (NTILES * 2)             // 1056 half-tiles (16 rows x 32 cols)
#define R1B 16
#define ROWS_PER_R1 (NHALF / R1B)      // 66

// workspace layout (floats)
#define OFF_WS2 (NHALF * BDIM)            // 135168
#define OFF_VT  (OFF_WS2 + R1B * BDIM)    // 137216
#define OFF_R   (OFF_VT + NDIM * BDIM)    // 268288; total 269312 fl ~ 1.05 MB

// 4-dispatch plain-store pipeline (gaps measured ~0 in R3/R5):
//   prep: VT[j][b] = V[b][j] (512 KB) + global masked rowsums R[1024].
//   main: NO LDS, NO barriers. Lane b reads vj/vi via coalesced global
//         b32 from VT; W rows are wave-uniform float4 (SGPR/L1 broadcast);
//         512 FMA/thread; coalesced partial store. The (1-v)*R terms are
//         attached only at diagonal-tile blocks (each row exactly once).
//   red1/red2: R7-proven coalesced two-stage fold.
// Rationale: across 5 variants main was pinned at ~20us while its work
// content is 2-4us; the shared invariant was per-block LDS transpose
// staging + barrier chain at ~2 waves/SIMD. This removes that entirely.

__global__ __launch_bounds__(256) void potts_prep(
    const float* __restrict__ V,      // [128][1024]
    const float* __restrict__ W,      // [1024][1024]
    float* __restrict__ VT,           // [1024][128]
    float* __restrict__ R)            // [1024]
{
    __shared__ float tr[TS][BDIM + 2];
    const int bid = blockIdx.x;
    const int tid = threadIdx.x;

    if (bid < 256) {
        // ---- masked rowsums: 4 rows/block, one wave per row
        const int wv = tid >> 6, l = tid & 63;
        const int i = 4 * bid + wv;
        const float* __restrict__ row = W + (size_t)i * NDIM;
        float s = 0.0f;
#pragma unroll
        for (int it = 0; it < 4; ++it) {
            const int c = 4 * l + 256 * it;
            float4 a = *(const float4*)(row + c);
            if (c + 0 < i) a.x = 0.0f;
            if (c + 1 < i) a.y = 0.0f;
            if (c + 2 < i) a.z = 0.0f;
            if (c + 3 < i) a.w = 0.0f;
            s += (a.x + a.y) + (a.z + a.w);
        }
        s += __shfl_xor(s, 1);
        s += __shfl_xor(s, 2);
        s += __shfl_xor(s, 4);
        s += __shfl_xor(s, 8);
        s += __shfl_xor(s, 16);
        s += __shfl_xor(s, 32);
        if (l == 0) R[i] = s;
    } else {
        // ---- V transpose, one 128b x 32j tile per block
        const int J0 = 32 * (bid - 256);
#pragma unroll
        for (int it = 0; it < 4; ++it) {
            const int fid = tid + 256 * it;        // 0..1023
            const int b = fid >> 3, c4 = (fid & 7) * 4;
            const float4 a = *(const float4*)(V + (size_t)b * NDIM + J0 + c4);
            tr[c4 + 0][b] = a.x; tr[c4 + 1][b] = a.y;
            tr[c4 + 2][b] = a.z; tr[c4 + 3][b] = a.w;
        }
        __syncthreads();
#pragma unroll
        for (int it = 0; it < 4; ++it) {
            const int fid = tid + 256 * it;        // 0..1023
            const int j = fid >> 5, b4 = (fid & 31) * 4;
            float4 o;
            o.x = tr[j][b4 + 0]; o.y = tr[j][b4 + 1];
            o.z = tr[j][b4 + 2]; o.w = tr[j][b4 + 3];
            *(float4*)(VT + (size_t)(J0 + j) * BDIM + b4) = o;   // coalesced
        }
    }
}

__global__ __launch_bounds__(128) void potts_main(
    const float* __restrict__ W,      // [1024][1024]
    const float* __restrict__ VT,     // [1024][128]
    const float* __restrict__ R,      // [1024]
    float* __restrict__ partial)      // [NHALF][BDIM]
{
    const int t2 = blockIdx.x;
    const int t = t2 >> 1, half = t2 & 1;
    // closed-form upper-tri tile index (verified rounds 1-7)
    const int u = NTILES - 1 - t;
    int kk = (int)(0.5f * (sqrtf((float)(8 * u + 1)) - 1.0f));
    if (kk * (kk + 1) / 2 > u) --kk;
    if ((kk + 1) * (kk + 2) / 2 <= u) ++kk;
    const int ti = NT - 1 - kk;
    const int tj = NT - 1 - (u - kk * (kk + 1) / 2);
    const int rbase = 16 * half;
    const int I0h = ti * TS + rbase;
    const int J0 = tj * TS;
    const bool diag = (ti == tj);

    const int tid = threadIdx.x;      // tid == b (lane l of wave w -> b=l+64w)

    // ---- coalesced global b32 loads, all independent, issued up front
    float vj[TS];
#pragma unroll
    for (int j = 0; j < TS; ++j)
        vj[j] = VT[(size_t)(J0 + j) * BDIM + tid];
    float vi[16];
#pragma unroll
    for (int il = 0; il < 16; ++il)
        vi[il] = VT[(size_t)(I0h + il) * BDIM + tid];

    float acc = 0.0f;
    if (diag) {                        // attach (1-v)*R terms once per row
#pragma unroll
        for (int il = 0; il < 16; ++il)
            acc = fmaf(1.0f - vi[il], R[I0h + il], acc);
    }

#pragma unroll
    for (int il = 0; il < 16; ++il) {
        const float* __restrict__ wr = W + (size_t)(I0h + il) * NDIM + J0;
        float za = 0.f, zb = 0.f;
#pragma unroll
        for (int j4 = 0; j4 < 8; j4 += 2) {
            float4 wa = *(const float4*)(wr + 4 * j4);       // wave-uniform
            float4 wb = *(const float4*)(wr + 4 * j4 + 4);   // wave-uniform
            if (diag) {                // triu: keep local col >= local row
                const int lr = rbase + il;
                if (4 * j4 + 0 < lr) wa.x = 0.0f;
                if (4 * j4 + 1 < lr) wa.y = 0.0f;
                if (4 * j4 + 2 < lr) wa.z = 0.0f;
                if (4 * j4 + 3 < lr) wa.w = 0.0f;
                if (4 * j4 + 4 < lr) wb.x = 0.0f;
                if (4 * j4 + 5 < lr) wb.y = 0.0f;
                if (4 * j4 + 6 < lr) wb.z = 0.0f;
                if (4 * j4 + 7 < lr) wb.w = 0.0f;
            }
            za = fmaf(wa.x, vj[4 * j4 + 0], za);
            za = fmaf(wa.y, vj[4 * j4 + 1], za);
            za = fmaf(wa.z, vj[4 * j4 + 2], za);
            za = fmaf(wa.w, vj[4 * j4 + 3], za);
            zb = fmaf(wb.x, vj[4 * j4 + 4], zb);
            zb = fmaf(wb.y, vj[4 * j4 + 5], zb);
            zb = fmaf(wb.z, vj[4 * j4 + 6], zb);
            zb = fmaf(wb.w, vj[4 * j4 + 7], zb);
        }
        acc = fmaf(2.0f * vi[il] - 1.0f, za + zb, acc);
    }

    partial[(size_t)t2 * BDIM + tid] = acc;      // coalesced plain store
}

// ---- red1: 16 blocks, each sums 66 contiguous partial rows (coalesced)
__global__ __launch_bounds__(256) void potts_red1(
    const float* __restrict__ partial, float* __restrict__ ws2)
{
    const int g = blockIdx.x;
    const int tid = threadIdx.x;
    const int b = tid & 127, h = tid >> 7;
    const float* __restrict__ base = partial + (size_t)g * ROWS_PER_R1 * BDIM;
    float a = 0.0f;
#pragma unroll
    for (int kx = 0; kx < ROWS_PER_R1 / 2; ++kx)
        a += base[(size_t)(2 * kx + h) * BDIM + b];
    __shared__ float s[256];
    s[tid] = a;
    __syncthreads();
    if (tid < BDIM) ws2[g * BDIM + tid] = s[tid] + s[tid + BDIM];
}

// ---- red2: 1 block folds 16 rows -> out[128]
__global__ __launch_bounds__(256) void potts_red2(
    const float* __restrict__ ws2, float* __restrict__ out)
{
    const int tid = threadIdx.x;
    const int b = tid & 127, h = tid >> 7;
    float a = 0.0f;
#pragma unroll
    for (int g = 0; g < R1B / 2; ++g)
        a += ws2[(2 * g + h) * BDIM + b];
    __shared__ float s[256];
    s[tid] = a;
    __syncthreads();
    if (tid < BDIM) out[tid] = s[tid] + s[tid + BDIM];
}

extern "C" void kernel_launch(void* const* d_in, const int* in_sizes, int n_in,
                              void* d_out, int out_size, void* d_ws, size_t ws_size,
                              hipStream_t stream) {
    const float* V = (const float*)d_in[0];
    const float* W = (const float*)d_in[1];
    float* out = (float*)d_out;
    float* ws = (float*)d_ws;
    float* partial = ws;
    float* ws2 = ws + OFF_WS2;
    float* VT = ws + OFF_VT;
    float* R  = ws + OFF_R;

    potts_prep<<<dim3(288), dim3(256), 0, stream>>>(V, W, VT, R);
    potts_main<<<dim3(NHALF), dim3(128), 0, stream>>>(W, VT, R, partial);
    potts_red1<<<dim3(R1B), dim3(256), 0, stream>>>(partial, ws2);
    potts_red2<<<dim3(1), dim3(256), 0, stream>>>(ws2, out);
}

// Round 9
// 65.252 us; speedup vs baseline: 1.5570x; 1.5570x over previous
//
#include <hip/hip_runtime.h>
#include <math.h>

#define NDIM 1024
#define BDIM 128
#define TS 32
#define NT (NDIM / TS)                 // 32
#define NTILES (NT * (NT + 1) / 2)     // 528 upper-tri tiles
#define NHALF (NTILES * 2)             // 1056 half-tiles (16 rows x 32 cols)
#define R1B 16                         // red1 block count
#define ROWS_PER_R1 (NHALF / R1B)      // 66

// MEASURED BEST (R7: 64.45us). Three-dispatch plain-store structure.
// Ledger of falsified alternatives (tail = dur - ~40.5us poison fill):
//   R0 528x256 LDS 4-wave: 24.3 | R7 this: 24.0 | R1 scalar-W: 26
//   R3 fence election: 67 | R4 atomic chain: 37 | R5 per-output: 93
//   R6 uncoalesced vi/stores: 31 | R8 no-LDS main: 61
// Main's ~20us vs ~4us model is invariant to instruction mix -> pinned by
// post-fill L2/L3 writeback drain + DVFS ramp, not by our code. Keep:
// coalesced float4 global loads, LDS-staged W (broadcast b128 in hot
// loop), 130-padded transposed V (2-way-free banks), coalesced stores,
// two-stage coalesced reduction.
__global__ __launch_bounds__(128) void potts_main(
    const float* __restrict__ V,      // [128][1024]
    const float* __restrict__ W,      // [1024][1024]
    float* __restrict__ partial)      // [NHALF][BDIM]
{
    const int t2 = blockIdx.x;
    const int t = t2 >> 1, half = t2 & 1;
    // closed-form upper-tri tile index (verified rounds 1-8)
    const int u = NTILES - 1 - t;
    int kk = (int)(0.5f * (sqrtf((float)(8 * u + 1)) - 1.0f));
    if (kk * (kk + 1) / 2 > u) --kk;
    if ((kk + 1) * (kk + 2) / 2 <= u) ++kk;
    const int ti = NT - 1 - kk;
    const int tj = NT - 1 - (u - kk * (kk + 1) / 2);
    const int rbase = 16 * half;          // local-row offset of this half
    const int I0h = ti * TS + rbase;      // absolute first row of half
    const int J0 = tj * TS;
    const bool diag = (ti == tj);

    __shared__ float wt[16][36];        // masked W half-tile, broadcast reads
    __shared__ float rs[16];            // masked row sums
    __shared__ float vjt[TS][130];      // V[:,J0+j] transposed [j][b]
    __shared__ float vit[16][130];      // V[:,I0h+i] transposed [i][b]
    __shared__ float red[2][BDIM];

    const int tid = threadIdx.x;        // 0..127
    const int w = tid >> 6;             // wave 0/1 -> rows 8w..8w+8
    const int l = tid & 63;

    // ---- W half-tile: 1 float4/thread (coalesced), mask, rowsum, stage
    {
        const int r = tid >> 3, c4 = (tid & 7) * 4;      // r: 0..15
        float4 w4 = *(const float4*)(W + (size_t)(I0h + r) * NDIM + (J0 + c4));
        if (diag) {                      // triu: keep local col >= local row
            const int lr = rbase + r;
            if (c4 + 0 < lr) w4.x = 0.0f;
            if (c4 + 1 < lr) w4.y = 0.0f;
            if (c4 + 2 < lr) w4.z = 0.0f;
            if (c4 + 3 < lr) w4.w = 0.0f;
        }
        *(float4*)(&wt[r][c4]) = w4;
        float rsum = (w4.x + w4.y) + (w4.z + w4.w);
        rsum += __shfl_xor(rsum, 1);
        rsum += __shfl_xor(rsum, 2);
        rsum += __shfl_xor(rsum, 4);
        if ((tid & 7) == 0) rs[r] = rsum;
    }

    // ---- stage vj: V[:,J0..J0+32] transposed (4096 floats, 8 iters)
#pragma unroll
    for (int it = 0; it < 8; ++it) {
        const int fid = tid + 128 * it;       // 0..1023
        const int b = fid >> 3, c4 = (fid & 7) * 4;
        const float4 a = *(const float4*)(V + (size_t)b * NDIM + (J0 + c4));
        vjt[c4 + 0][b] = a.x; vjt[c4 + 1][b] = a.y;
        vjt[c4 + 2][b] = a.z; vjt[c4 + 3][b] = a.w;
    }
    // ---- stage vi: V[:,I0h..I0h+16] transposed (2048 floats, 4 iters)
#pragma unroll
    for (int it = 0; it < 4; ++it) {
        const int fid = tid + 128 * it;       // 0..511
        const int b = fid >> 2, c4 = (fid & 3) * 4;
        const float4 a = *(const float4*)(V + (size_t)b * NDIM + (I0h + c4));
        vit[c4 + 0][b] = a.x; vit[c4 + 1][b] = a.y;
        vit[c4 + 2][b] = a.z; vit[c4 + 3][b] = a.w;
    }
    __syncthreads();

    // ---- per-lane vj registers (2-way-free LDS reads)
    float vj0[TS], vj1[TS];
#pragma unroll
    for (int j = 0; j < TS; ++j) {
        vj0[j] = vjt[j][l];
        vj1[j] = vjt[j][l + 64];
    }

    float acc0 = 0.0f, acc1 = 0.0f;
#pragma unroll
    for (int k = 0; k < 8; ++k) {
        const int il = 8 * w + k;             // 0..15 within half
        const float vi0 = vit[il][l], vi1 = vit[il][l + 64];
        const float* wrow = &wt[il][0];
        float za0 = 0.f, zb0 = 0.f, za1 = 0.f, zb1 = 0.f;
#pragma unroll
        for (int j4 = 0; j4 < 8; j4 += 2) {
            const float4 wa = *(const float4*)(wrow + 4 * j4);     // broadcast
            const float4 wb = *(const float4*)(wrow + 4 * j4 + 4); // broadcast
            za0 = fmaf(wa.x, vj0[4 * j4 + 0], za0);
            za0 = fmaf(wa.y, vj0[4 * j4 + 1], za0);
            za0 = fmaf(wa.z, vj0[4 * j4 + 2], za0);
            za0 = fmaf(wa.w, vj0[4 * j4 + 3], za0);
            za1 = fmaf(wa.x, vj1[4 * j4 + 0], za1);
            za1 = fmaf(wa.y, vj1[4 * j4 + 1], za1);
            za1 = fmaf(wa.z, vj1[4 * j4 + 2], za1);
            za1 = fmaf(wa.w, vj1[4 * j4 + 3], za1);
            zb0 = fmaf(wb.x, vj0[4 * j4 + 4], zb0);
            zb0 = fmaf(wb.y, vj0[4 * j4 + 5], zb0);
            zb0 = fmaf(wb.z, vj0[4 * j4 + 6], zb0);
            zb0 = fmaf(wb.w, vj0[4 * j4 + 7], zb0);
            zb1 = fmaf(wb.x, vj1[4 * j4 + 4], zb1);
            zb1 = fmaf(wb.y, vj1[4 * j4 + 5], zb1);
            zb1 = fmaf(wb.z, vj1[4 * j4 + 6], zb1);
            zb1 = fmaf(wb.w, vj1[4 * j4 + 7], zb1);
        }
        const float rsk = rs[il];
        acc0 = fmaf(1.0f - vi0, rsk, acc0);
        acc0 = fmaf(2.0f * vi0 - 1.0f, za0 + zb0, acc0);
        acc1 = fmaf(1.0f - vi1, rsk, acc1);
        acc1 = fmaf(2.0f * vi1 - 1.0f, za1 + zb1, acc1);
    }

    // ---- block reduce (2 waves), coalesced plain store partial[t2][b]
    red[w][l] = acc0;
    red[w][l + 64] = acc1;
    __syncthreads();
    if (tid < BDIM) {
        partial[(size_t)t2 * BDIM + tid] = red[0][tid] + red[1][tid];
    }
}

// ---- red1: 16 blocks, each sums 66 contiguous partial rows (coalesced)
__global__ __launch_bounds__(256) void potts_red1(
    const float* __restrict__ partial, float* __restrict__ ws2)
{
    const int g = blockIdx.x;            // 0..15
    const int tid = threadIdx.x;
    const int b = tid & 127, h = tid >> 7;
    const float* __restrict__ base = partial + (size_t)g * ROWS_PER_R1 * BDIM;
    float a = 0.0f;
#pragma unroll
    for (int kx = 0; kx < ROWS_PER_R1 / 2; ++kx)     // 33 coalesced loads
        a += base[(size_t)(2 * kx + h) * BDIM + b];
    __shared__ float s[256];
    s[tid] = a;
    __syncthreads();
    if (tid < BDIM) ws2[g * BDIM + tid] = s[tid] + s[tid + BDIM];
}

// ---- red2: 1 block folds 16 rows -> out[128] (coalesced)
__global__ __launch_bounds__(256) void potts_red2(
    const float* __restrict__ ws2, float* __restrict__ out)
{
    const int tid = threadIdx.x;
    const int b = tid & 127, h = tid >> 7;
    float a = 0.0f;
#pragma unroll
    for (int g = 0; g < R1B / 2; ++g)                // 8 coalesced loads
        a += ws2[(2 * g + h) * BDIM + b];
    __shared__ float s[256];
    s[tid] = a;
    __syncthreads();
    if (tid < BDIM) out[tid] = s[tid] + s[tid + BDIM];
}

extern "C" void kernel_launch(void* const* d_in, const int* in_sizes, int n_in,
                              void* d_out, int out_size, void* d_ws, size_t ws_size,
                              hipStream_t stream) {
    const float* V = (const float*)d_in[0];
    const float* W = (const float*)d_in[1];
    float* out = (float*)d_out;
    float* partial = (float*)d_ws;                    // NHALF*128*4 = 540672 B
    float* ws2 = partial + (size_t)NHALF * BDIM;      // +16*128*4 = 8 KB

    potts_main<<<dim3(NHALF), dim3(128), 0, stream>>>(V, W, partial);
    potts_red1<<<dim3(R1B), dim3(256), 0, stream>>>(partial, ws2);
    potts_red2<<<dim3(1), dim3(256), 0, stream>>>(ws2, out);
}